// Round 4
// baseline (1602.698 us; speedup 1.0000x reference)
//
#include <hip/hip_runtime.h>
#include <hip/hip_bf16.h>

#define NTOK 16384
#define HID 7168
#define NEXP 256
#define TOPK 8

#define BT 64                 // tokens per block
#define BK 16                 // k-chunk per step
#define NSTEP (HID / BK)      // 448
#define LDK 20                // padded k-stride in words

// row_idx is input-independent: row[t][k] = k*NTOK + t, float, chunk 2 only.
__global__ void moe_rows(float* __restrict__ ob) {
    const int q = blockIdx.x * 256 + threadIdx.x;   // 0 .. 131071
    const int r = q & 7;
    const int t = q >> 3;
    ob[262144 + q] = (float)(r * NTOK + t);
}

__global__ __launch_bounds__(256, 1) void moe_gate(
    const float* __restrict__ hs,
    const float* __restrict__ wt,
    float* __restrict__ ob)
{
    __shared__ float h_lds[BT * LDK];        //  5.1 KB
    __shared__ float w_lds[NEXP * LDK];      // 20.5 KB
    __shared__ float l_lds[16][NEXP + 1];    // 16.4 KB  (16 tokens x 256 logits)

    const int tid = threadIdx.x;
    const int blk = blockIdx.x;
    const int t0  = blk * BT;

    // staging map: thread -> (row, 4-float k-slice)
    const int srow = tid >> 2;            // 0..63
    const int skol = (tid & 3) << 2;      // 0,4,8,12

    const float* ap = hs + (size_t)(t0 + srow) * HID + skol;
    const float* bp = wt + (size_t)srow * HID + skol;

    // compute map: ty = token group (4 tokens), tx = expert lane (16 strided experts)
    const int ty = tid >> 4;              // 0..15
    const int tx = tid & 15;              // 0..15 ; expert e = tx + 16*j

    float acc[4][16];
    #pragma unroll
    for (int i = 0; i < 4; ++i)
        #pragma unroll
        for (int j = 0; j < 16; ++j) acc[i][j] = 0.f;

    // prefetch step 0 into registers
    float4 ra  = *(const float4*)(ap);
    float4 rb0 = *(const float4*)(bp);
    float4 rb1 = *(const float4*)(bp +  64 * HID);
    float4 rb2 = *(const float4*)(bp + 128 * HID);
    float4 rb3 = *(const float4*)(bp + 192 * HID);

    for (int s = 0; s < NSTEP; ++s) {
        *(float4*)&h_lds[srow * LDK + skol]          = ra;
        *(float4*)&w_lds[srow * LDK + skol]          = rb0;
        *(float4*)&w_lds[(srow +  64) * LDK + skol]  = rb1;
        *(float4*)&w_lds[(srow + 128) * LDK + skol]  = rb2;
        *(float4*)&w_lds[(srow + 192) * LDK + skol]  = rb3;
        __syncthreads();

        if (s + 1 < NSTEP) {
            const int off = (s + 1) * BK;
            ra  = *(const float4*)(ap + off);
            rb0 = *(const float4*)(bp + off);
            rb1 = *(const float4*)(bp +  64 * HID + off);
            rb2 = *(const float4*)(bp + 128 * HID + off);
            rb3 = *(const float4*)(bp + 192 * HID + off);
        }

        #pragma unroll
        for (int k4 = 0; k4 < 4; ++k4) {
            float4 hv[4];
            #pragma unroll
            for (int i = 0; i < 4; ++i)
                hv[i] = *(const float4*)&h_lds[(ty * 4 + i) * LDK + k4 * 4];
            #pragma unroll
            for (int j = 0; j < 16; ++j) {
                float4 w = *(const float4*)&w_lds[(tx + 16 * j) * LDK + k4 * 4];
                #pragma unroll
                for (int i = 0; i < 4; ++i) {
                    acc[i][j] = fmaf(hv[i].x, w.x, acc[i][j]);
                    acc[i][j] = fmaf(hv[i].y, w.y, acc[i][j]);
                    acc[i][j] = fmaf(hv[i].z, w.z, acc[i][j]);
                    acc[i][j] = fmaf(hv[i].w, w.w, acc[i][j]);
                }
            }
        }
        __syncthreads();
    }

    // ---- epilogue: serial, shuffle-free top-8 via LDS ----
    for (int i = 0; i < 4; ++i) {
        // stage logits for the 16 tokens {ty*4+i}: row ty, expert tx+16*j
        #pragma unroll
        for (int j = 0; j < 16; ++j)
            l_lds[ty][tx + 16 * j] = acc[i][j];
        __syncthreads();

        if (tid < 16) {
            const int w = tid;                    // token row in l_lds
            float bv[TOPK]; int bi8[TOPK];
            #pragma unroll
            for (int k = 0; k < TOPK; ++k) { bv[k] = -1e30f; bi8[k] = 0; }

            for (int e = 0; e < NEXP; ++e) {
                const float v = l_lds[w][e];
                if (v > bv[TOPK - 1]) {
                    int k = TOPK - 1;
                    while (k > 0 && v > bv[k - 1]) {
                        bv[k] = bv[k - 1]; bi8[k] = bi8[k - 1]; --k;
                    }
                    bv[k] = v; bi8[k] = e;        // strict > : ties keep lower idx
                }
            }

            // normalized top-k softmax weights (full-softmax Z cancels)
            float ev[TOPK];
            float ssum = 0.f;
            const float m = bv[0];
            #pragma unroll
            for (int r = 0; r < TOPK; ++r) { ev[r] = expf(bv[r] - m); ssum += ev[r]; }
            const float inv = 1.0f / ssum;

            const int tg = t0 + w * 4 + i;
            #pragma unroll
            for (int r = 0; r < TOPK; ++r) {
                ob[(size_t)tg * TOPK + r]          = (float)bi8[r];   // chunk 0: idx
                ob[131072 + (size_t)tg * TOPK + r] = ev[r] * inv;     // chunk 1: weight
            }
        }
        __syncthreads();
    }
}

extern "C" void kernel_launch(void* const* d_in, const int* in_sizes, int n_in,
                              void* d_out, int out_size, void* d_ws, size_t ws_size,
                              hipStream_t stream) {
    const float* hs = (const float*)d_in[0];   // [16384, 7168] f32
    const float* wt = (const float*)d_in[1];   // [256, 7168] f32
    float* ob = (float*)d_out;                 // f32[393216]: idx | weight | row
    moe_gate<<<dim3(NTOK / BT), dim3(256), 0, stream>>>(hs, wt, ob);
    moe_rows<<<dim3(512), dim3(256), 0, stream>>>(ob);
}

// Round 6
// 255.037 us; speedup vs baseline: 6.2842x; 6.2842x over previous
//
#include <hip/hip_runtime.h>
#include <hip/hip_bf16.h>

#define NTOK 16384
#define HID 7168
#define NEXP 256
#define TOPK 8

#define BT 64                  // tokens per block
#define BK 64                  // k per chunk
#define NCH (HID / BK)         // 112

typedef __bf16 bf16x8 __attribute__((ext_vector_type(8)));
typedef float  f32x16 __attribute__((ext_vector_type(16)));

// RTNE f32 -> bf16 bits
__device__ __forceinline__ unsigned int f2bfb(float x) {
    unsigned int u = __float_as_uint(x);
    return (u + 0x7fffu + ((u >> 16) & 1u)) >> 16;
}

// ---- pre-convert weight f32 -> bf16 into workspace (3.67 MB) ----
__global__ void wconv(const float* __restrict__ wt, unsigned short* __restrict__ wb) {
    const int i = blockIdx.x * 256 + threadIdx.x;       // over NEXP*HID/4 float4s
    const float4 v = ((const float4*)wt)[i];
    uint2 o;
    o.x = f2bfb(v.x) | (f2bfb(v.y) << 16);
    o.y = f2bfb(v.z) | (f2bfb(v.w) << 16);
    ((uint2*)wb)[i] = o;
}

// row_idx is input-independent: row[t][k] = k*NTOK + t (chunk 2)
__global__ void moe_rows(float* __restrict__ ob) {
    const int q = blockIdx.x * 256 + threadIdx.x;       // 0 .. 131071
    ob[262144 + q] = (float)((q & 7) * NTOK + (q >> 3));
}

template<bool PRECONV>
__global__ __launch_bounds__(512) void moe_gate_mfma(
    const float* __restrict__ hs,
    const float* __restrict__ wt,
    const unsigned short* __restrict__ wb,
    float* __restrict__ ob)
{
    // smem: bufA[2] @ 0 (2x8 KB), bufB[2] @ 16384 (2x32 KB)  => 80 KB
    // epilogue aliases logits [64][257] f32 (65.8 KB) over the same region
    __shared__ __align__(16) char smem[81920];

    const int tid  = threadIdx.x;
    const int t0   = blockIdx.x * BT;
    const int lane = tid & 63;
    const int wv   = tid >> 6;        // 0..7
    const int wm   = wv >> 2;         // 0..1  (token half)
    const int wn   = wv & 3;          // 0..3  (expert quarter)

    // ---- staging maps ----
    // A: 1024 items (row 0..63, colgroup 0..15 of 4 f32); thread does items tid, tid+512
    const int arow = tid >> 4;                    // 0..31 (and +32)
    const int acg  = tid & 15;
    const float* apt = hs + (size_t)(t0 + arow) * HID + acg * 4;
    const int aswz0 = (arow * 128 + acg * 8) ^ ((arow & 7) << 4);
    const int aswz1 = ((arow + 32) * 128 + acg * 8) ^ ((arow & 7) << 4);

    // B: 2048 items (exp row 0..255, kgroup 0..7 of 8 bf16 = 16 B) -> 4 items/thread
    // row_i = (tid>>3) + i*64, kg = tid&7 ; (i*64 preserves row&7 so swizzle is shared)
    const int brow = tid >> 3;                    // 0..63 (then +64,+128,+192)
    const int bkg  = tid & 7;
    const unsigned short* bpt = PRECONV ? (wb + (size_t)brow * HID + bkg * 8) : (const unsigned short*)0;
    const int bsw  = ((brow & 7) << 4);
    const int bofs0 = ((brow      ) * 128 + bkg * 16) ^ bsw;
    const int bofs1 = ((brow +  64) * 128 + bkg * 16) ^ bsw;
    const int bofs2 = ((brow + 128) * 128 + bkg * 16) ^ bsw;
    const int bofs3 = ((brow + 192) * 128 + bkg * 16) ^ bsw;

    // B (fallback f32): same rows, load 8 f32 per item instead
    const float* fpt = wt + (size_t)brow * HID + bkg * 8;

    // ---- fragment read offsets ----
    const int kl   = (lane >> 5) * 16;            // 16B half-select within K=16
    const int swz  = (lane & 7) << 4;
    const int frA  = (wm * 32 + (lane & 31)) * 128;
    const int erB0 = (wn * 64 + (lane & 31)) * 128;
    const int erB1 = erB0 + 32 * 128;

    f32x16 acc0 = {};
    f32x16 acc1 = {};

    float4 ra0, ra1;
    uint4  rb0, rb1, rb2, rb3;
    float4 rf0, rf1, rf2, rf3, rf4, rf5, rf6, rf7;

    auto loadA = [&](int s) {
        ra0 = *(const float4*)(apt + s * BK);
        ra1 = *(const float4*)(apt + (size_t)32 * HID + s * BK);
    };
    auto loadB = [&](int s) {
        if constexpr (PRECONV) {
            rb0 = *(const uint4*)(bpt + s * BK);
            rb1 = *(const uint4*)(bpt + (size_t)64  * HID + s * BK);
            rb2 = *(const uint4*)(bpt + (size_t)128 * HID + s * BK);
            rb3 = *(const uint4*)(bpt + (size_t)192 * HID + s * BK);
        } else {
            const float* p = fpt + s * BK;
            rf0 = *(const float4*)(p);                         rf1 = *(const float4*)(p + 4);
            rf2 = *(const float4*)(p + (size_t)64 * HID);      rf3 = *(const float4*)(p + (size_t)64 * HID + 4);
            rf4 = *(const float4*)(p + (size_t)128 * HID);     rf5 = *(const float4*)(p + (size_t)128 * HID + 4);
            rf6 = *(const float4*)(p + (size_t)192 * HID);     rf7 = *(const float4*)(p + (size_t)192 * HID + 4);
        }
    };
    auto writeA = [&](char* bA) {
        uint2 u0, u1;
        u0.x = f2bfb(ra0.x) | (f2bfb(ra0.y) << 16);
        u0.y = f2bfb(ra0.z) | (f2bfb(ra0.w) << 16);
        u1.x = f2bfb(ra1.x) | (f2bfb(ra1.y) << 16);
        u1.y = f2bfb(ra1.z) | (f2bfb(ra1.w) << 16);
        *(uint2*)(bA + aswz0) = u0;
        *(uint2*)(bA + aswz1) = u1;
    };
    auto writeB = [&](char* bB) {
        if constexpr (PRECONV) {
            *(uint4*)(bB + bofs0) = rb0;
            *(uint4*)(bB + bofs1) = rb1;
            *(uint4*)(bB + bofs2) = rb2;
            *(uint4*)(bB + bofs3) = rb3;
        } else {
            uint4 u;
            u.x = f2bfb(rf0.x) | (f2bfb(rf0.y) << 16); u.y = f2bfb(rf0.z) | (f2bfb(rf0.w) << 16);
            u.z = f2bfb(rf1.x) | (f2bfb(rf1.y) << 16); u.w = f2bfb(rf1.z) | (f2bfb(rf1.w) << 16);
            *(uint4*)(bB + bofs0) = u;
            u.x = f2bfb(rf2.x) | (f2bfb(rf2.y) << 16); u.y = f2bfb(rf2.z) | (f2bfb(rf2.w) << 16);
            u.z = f2bfb(rf3.x) | (f2bfb(rf3.y) << 16); u.w = f2bfb(rf3.z) | (f2bfb(rf3.w) << 16);
            *(uint4*)(bB + bofs1) = u;
            u.x = f2bfb(rf4.x) | (f2bfb(rf4.y) << 16); u.y = f2bfb(rf4.z) | (f2bfb(rf4.w) << 16);
            u.z = f2bfb(rf5.x) | (f2bfb(rf5.y) << 16); u.w = f2bfb(rf5.z) | (f2bfb(rf5.w) << 16);
            *(uint4*)(bB + bofs2) = u;
            u.x = f2bfb(rf6.x) | (f2bfb(rf6.y) << 16); u.y = f2bfb(rf6.z) | (f2bfb(rf6.w) << 16);
            u.z = f2bfb(rf7.x) | (f2bfb(rf7.y) << 16); u.w = f2bfb(rf7.z) | (f2bfb(rf7.w) << 16);
            *(uint4*)(bB + bofs3) = u;
        }
    };
    auto compute = [&](const char* bA, const char* bB) {
        #pragma unroll
        for (int kk = 0; kk < 4; ++kk) {
            const int c = (kk * 32 + kl) ^ swz;
            bf16x8 a  = *(const bf16x8*)(bA + frA  + c);
            bf16x8 b0 = *(const bf16x8*)(bB + erB0 + c);
            bf16x8 b1 = *(const bf16x8*)(bB + erB1 + c);
            acc0 = __builtin_amdgcn_mfma_f32_32x32x16_bf16(a, b0, acc0, 0, 0, 0);
            acc1 = __builtin_amdgcn_mfma_f32_32x32x16_bf16(a, b1, acc1, 0, 0, 0);
        }
    };

    // ---- pipelined K loop: one barrier per chunk ----
    loadA(0); loadB(0);
    writeA(smem); writeB(smem + 16384);
    __syncthreads();
    for (int s = 0; s < NCH; ++s) {
        char* curA = smem + (s & 1) * 8192;
        char* curB = smem + 16384 + (s & 1) * 32768;
        if (s + 1 < NCH) { loadA(s + 1); loadB(s + 1); }
        compute(curA, curB);
        if (s + 1 < NCH) {
            writeA(smem + ((s + 1) & 1) * 8192);
            writeB(smem + 16384 + ((s + 1) & 1) * 32768);
        }
        __syncthreads();
    }

    // ---- epilogue: dump logits to LDS [64][257] f32 ----
    float* ll = (float*)smem;
    {
        const int e0 = wn * 64 + (lane & 31);
        const int rb = wm * 32 + 4 * (lane >> 5);
        #pragma unroll
        for (int r = 0; r < 16; ++r) {
            const int tok = rb + (r & 3) + 8 * (r >> 2);
            ll[tok * 257 + e0]      = acc0[r];
            ll[tok * 257 + e0 + 32] = acc1[r];
        }
    }
    __syncthreads();

    if (tid < 64) {
        const float* lr = ll + tid * 257;
        float bv[TOPK]; int bi8[TOPK];
        #pragma unroll
        for (int k = 0; k < TOPK; ++k) { bv[k] = -1e30f; bi8[k] = 0; }
        for (int e = 0; e < NEXP; ++e) {
            const float v = lr[e];
            if (v > bv[TOPK - 1]) {
                int k = TOPK - 1;
                while (k > 0 && v > bv[k - 1]) {
                    bv[k] = bv[k - 1]; bi8[k] = bi8[k - 1]; --k;
                }
                bv[k] = v; bi8[k] = e;          // strict > : ties keep lower idx
            }
        }
        float ev[TOPK], ssum = 0.f;
        #pragma unroll
        for (int r = 0; r < TOPK; ++r) { ev[r] = expf(bv[r] - bv[0]); ssum += ev[r]; }
        const float inv = 1.0f / ssum;

        const int tg = t0 + tid;
        #pragma unroll
        for (int r = 0; r < TOPK; ++r) {
            ob[(size_t)tg * TOPK + r]          = (float)bi8[r];   // chunk 0: idx
            ob[131072 + (size_t)tg * TOPK + r] = ev[r] * inv;     // chunk 1: weight
        }
    }
}

extern "C" void kernel_launch(void* const* d_in, const int* in_sizes, int n_in,
                              void* d_out, int out_size, void* d_ws, size_t ws_size,
                              hipStream_t stream) {
    const float* hs = (const float*)d_in[0];   // [16384, 7168] f32
    const float* wt = (const float*)d_in[1];   // [256, 7168] f32
    float* ob = (float*)d_out;                 // f32[393216]: idx | weight | row

    if (ws_size >= (size_t)NEXP * HID * 2) {
        unsigned short* wb = (unsigned short*)d_ws;
        wconv<<<dim3(NEXP * HID / 4 / 256), dim3(256), 0, stream>>>(wt, wb);
        moe_gate_mfma<true><<<dim3(NTOK / BT), dim3(512), 0, stream>>>(hs, wt, wb, ob);
    } else {
        moe_gate_mfma<false><<<dim3(NTOK / BT), dim3(512), 0, stream>>>(hs, wt, nullptr, ob);
    }
    moe_rows<<<dim3(512), dim3(256), 0, stream>>>(ob);
}

// Round 7
// 254.273 us; speedup vs baseline: 6.3031x; 1.0030x over previous
//
#include <hip/hip_runtime.h>
#include <hip/hip_bf16.h>

#define NTOK 16384
#define HID 7168
#define NEXP 256
#define TOPK 8

#define BT 32                  // tokens per block
#define BK 64                  // k per chunk
#define NCH (HID / BK)         // 112  (even -> clean x2 unroll)

typedef __bf16 bf16x8 __attribute__((ext_vector_type(8)));
typedef float  f32x16 __attribute__((ext_vector_type(16)));

// RTNE f32 -> bf16 bits
__device__ __forceinline__ unsigned int f2bfb(float x) {
    unsigned int u = __float_as_uint(x);
    return (u + 0x7fffu + ((u >> 16) & 1u)) >> 16;
}

// ---- pre-convert weight f32 -> bf16 into workspace (3.67 MB) ----
__global__ void wconv(const float* __restrict__ wt, unsigned short* __restrict__ wb) {
    const int i = blockIdx.x * 256 + threadIdx.x;
    const float4 v = ((const float4*)wt)[i];
    uint2 o;
    o.x = f2bfb(v.x) | (f2bfb(v.y) << 16);
    o.y = f2bfb(v.z) | (f2bfb(v.w) << 16);
    ((uint2*)wb)[i] = o;
}

// row_idx: row[t][k] = k*NTOK + t (chunk 2)
__global__ void moe_rows(float* __restrict__ ob) {
    const int q = blockIdx.x * 256 + threadIdx.x;
    ob[262144 + q] = (float)((q & 7) * NTOK + (q >> 3));
}

// LDS layout (72 KB/block => 2 blocks/CU):
//   bufA0 @0      (4 KB)   bufA1 @4096   (4 KB)
//   bufB0 @8192   (32 KB)  bufB1 @40960  (32 KB)
// epilogue aliases logits [32][257] f32 (32.1 KB) over the same region.
template<bool PRECONV>
__global__ __launch_bounds__(512, 4) void moe_gate_mfma(
    const float* __restrict__ hs,
    const float* __restrict__ wt,
    const unsigned short* __restrict__ wb,
    float* __restrict__ ob)
{
    __shared__ __align__(16) char smem[73728];

    const int tid  = threadIdx.x;
    const int t0   = blockIdx.x * BT;
    const int lane = tid & 63;
    const int wv   = tid >> 6;        // 0..7: expert slice [wv*32, wv*32+32)

    // ---- staging maps ----
    // A: 512 items (tok 0..31 x 16 colgroups of 4 f32), 1 per thread
    const int arow = tid >> 4;                    // 0..31
    const int acg  = tid & 15;
    const float* apt = hs + (size_t)(t0 + arow) * HID + acg * 4;
    const int aofs = (arow * 128 + acg * 8) ^ ((arow & 7) << 4);

    // B: 2048 items (exp 0..255 x 8 kgroups of 16 B), 4 per thread
    const int brow = tid >> 3;                    // 0..63 (+64,+128,+192)
    const int bkg  = tid & 7;
    const unsigned short* bpt = PRECONV ? (wb + (size_t)brow * HID + bkg * 8) : (const unsigned short*)0;
    const float* fpt = wt + (size_t)brow * HID + bkg * 8;
    const int bsw  = ((brow & 7) << 4);
    const int bofs0 = ((brow      ) * 128 + bkg * 16) ^ bsw;
    const int bofs1 = ((brow +  64) * 128 + bkg * 16) ^ bsw;
    const int bofs2 = ((brow + 128) * 128 + bkg * 16) ^ bsw;
    const int bofs3 = ((brow + 192) * 128 + bkg * 16) ^ bsw;

    // ---- fragment read offsets ----
    const int kl  = (lane >> 5) * 16;
    const int swz = (lane & 7) << 4;
    const int frA = (lane & 31) * 128;
    const int erB = (wv * 32 + (lane & 31)) * 128;

    f32x16 acc = {};

    // two static register sets (depth-2 pipeline)
    float4 ra_0, ra_1;
    uint4  rb0_0, rb1_0, rb2_0, rb3_0;
    uint4  rb0_1, rb1_1, rb2_1, rb3_1;
    float4 rf0_0, rf1_0, rf2_0, rf3_0, rf4_0, rf5_0, rf6_0, rf7_0;
    float4 rf0_1, rf1_1, rf2_1, rf3_1, rf4_1, rf5_1, rf6_1, rf7_1;

#define LOAD_SET(SET, s)                                                          \
    do {                                                                          \
        ra_##SET = *(const float4*)(apt + (s) * BK);                              \
        if constexpr (PRECONV) {                                                  \
            rb0_##SET = *(const uint4*)(bpt + (s) * BK);                          \
            rb1_##SET = *(const uint4*)(bpt + (size_t)64  * HID + (s) * BK);      \
            rb2_##SET = *(const uint4*)(bpt + (size_t)128 * HID + (s) * BK);      \
            rb3_##SET = *(const uint4*)(bpt + (size_t)192 * HID + (s) * BK);      \
        } else {                                                                  \
            const float* p = fpt + (s) * BK;                                      \
            rf0_##SET = *(const float4*)(p);                                      \
            rf1_##SET = *(const float4*)(p + 4);                                  \
            rf2_##SET = *(const float4*)(p + (size_t)64 * HID);                   \
            rf3_##SET = *(const float4*)(p + (size_t)64 * HID + 4);               \
            rf4_##SET = *(const float4*)(p + (size_t)128 * HID);                  \
            rf5_##SET = *(const float4*)(p + (size_t)128 * HID + 4);              \
            rf6_##SET = *(const float4*)(p + (size_t)192 * HID);                  \
            rf7_##SET = *(const float4*)(p + (size_t)192 * HID + 4);              \
        }                                                                         \
    } while (0)

#define WRITE_SET(SET, bA, bB)                                                    \
    do {                                                                          \
        uint2 ua;                                                                 \
        ua.x = f2bfb(ra_##SET.x) | (f2bfb(ra_##SET.y) << 16);                     \
        ua.y = f2bfb(ra_##SET.z) | (f2bfb(ra_##SET.w) << 16);                     \
        *(uint2*)((bA) + aofs) = ua;                                              \
        if constexpr (PRECONV) {                                                  \
            *(uint4*)((bB) + bofs0) = rb0_##SET;                                  \
            *(uint4*)((bB) + bofs1) = rb1_##SET;                                  \
            *(uint4*)((bB) + bofs2) = rb2_##SET;                                  \
            *(uint4*)((bB) + bofs3) = rb3_##SET;                                  \
        } else {                                                                  \
            uint4 u;                                                              \
            u.x = f2bfb(rf0_##SET.x) | (f2bfb(rf0_##SET.y) << 16);                \
            u.y = f2bfb(rf0_##SET.z) | (f2bfb(rf0_##SET.w) << 16);                \
            u.z = f2bfb(rf1_##SET.x) | (f2bfb(rf1_##SET.y) << 16);                \
            u.w = f2bfb(rf1_##SET.z) | (f2bfb(rf1_##SET.w) << 16);                \
            *(uint4*)((bB) + bofs0) = u;                                          \
            u.x = f2bfb(rf2_##SET.x) | (f2bfb(rf2_##SET.y) << 16);                \
            u.y = f2bfb(rf2_##SET.z) | (f2bfb(rf2_##SET.w) << 16);                \
            u.z = f2bfb(rf3_##SET.x) | (f2bfb(rf3_##SET.y) << 16);                \
            u.w = f2bfb(rf3_##SET.z) | (f2bfb(rf3_##SET.w) << 16);                \
            *(uint4*)((bB) + bofs1) = u;                                          \
            u.x = f2bfb(rf4_##SET.x) | (f2bfb(rf4_##SET.y) << 16);                \
            u.y = f2bfb(rf4_##SET.z) | (f2bfb(rf4_##SET.w) << 16);                \
            u.z = f2bfb(rf5_##SET.x) | (f2bfb(rf5_##SET.y) << 16);                \
            u.w = f2bfb(rf5_##SET.z) | (f2bfb(rf5_##SET.w) << 16);                \
            *(uint4*)((bB) + bofs2) = u;                                          \
            u.x = f2bfb(rf6_##SET.x) | (f2bfb(rf6_##SET.y) << 16);                \
            u.y = f2bfb(rf6_##SET.z) | (f2bfb(rf6_##SET.w) << 16);                \
            u.z = f2bfb(rf7_##SET.x) | (f2bfb(rf7_##SET.y) << 16);                \
            u.w = f2bfb(rf7_##SET.z) | (f2bfb(rf7_##SET.w) << 16);                \
            *(uint4*)((bB) + bofs3) = u;                                          \
        }                                                                         \
    } while (0)

    char* const bA0 = smem;
    char* const bA1 = smem + 4096;
    char* const bB0 = smem + 8192;
    char* const bB1 = smem + 40960;

    auto compute = [&](const char* bA, const char* bB) {
        #pragma unroll
        for (int kk = 0; kk < 4; ++kk) {
            const int c = (kk * 32 + kl) ^ swz;
            bf16x8 a = *(const bf16x8*)(bA + frA + c);
            bf16x8 b = *(const bf16x8*)(bB + erB + c);
            acc = __builtin_amdgcn_mfma_f32_32x32x16_bf16(a, b, acc, 0, 0, 0);
        }
    };

    // ---- depth-2 pipelined K loop (x2 unrolled, static reg sets) ----
    LOAD_SET(0, 0);
    LOAD_SET(1, 1);
    WRITE_SET(0, bA0, bB0);
    __syncthreads();

    for (int s = 0; s < NCH; s += 2) {
        // even half: compute chunk s from buf0
        if (s + 2 < NCH) LOAD_SET(0, s + 2);
        compute(bA0, bB0);
        WRITE_SET(1, bA1, bB1);          // chunk s+1 (loaded one iter ago)
        __syncthreads();

        // odd half: compute chunk s+1 from buf1
        if (s + 3 < NCH) LOAD_SET(1, s + 3);
        compute(bA1, bB1);
        if (s + 2 < NCH) WRITE_SET(0, bA0, bB0);   // chunk s+2
        __syncthreads();
    }

    // ---- epilogue: dump logits to LDS [32][257] f32 ----
    float* ll = (float*)smem;
    {
        const int e0 = wv * 32 + (lane & 31);
        const int rb = 4 * (lane >> 5);
        #pragma unroll
        for (int r = 0; r < 16; ++r) {
            const int tok = rb + (r & 3) + 8 * (r >> 2);
            ll[tok * 257 + e0] = acc[r];
        }
    }
    __syncthreads();

    if (tid < BT) {
        const float* lr = ll + tid * 257;
        float bv[TOPK]; int bi8[TOPK];
        #pragma unroll
        for (int k = 0; k < TOPK; ++k) { bv[k] = -1e30f; bi8[k] = 0; }
        for (int e = 0; e < NEXP; ++e) {
            const float v = lr[e];
            if (v > bv[TOPK - 1]) {
                int k = TOPK - 1;
                while (k > 0 && v > bv[k - 1]) {
                    bv[k] = bv[k - 1]; bi8[k] = bi8[k - 1]; --k;
                }
                bv[k] = v; bi8[k] = e;          // strict > : ties keep lower idx
            }
        }
        float ev[TOPK], ssum = 0.f;
        #pragma unroll
        for (int r = 0; r < TOPK; ++r) { ev[r] = expf(bv[r] - bv[0]); ssum += ev[r]; }
        const float inv = 1.0f / ssum;

        const int tg = t0 + tid;
        #pragma unroll
        for (int r = 0; r < TOPK; ++r) {
            ob[(size_t)tg * TOPK + r]          = (float)bi8[r];   // chunk 0: idx
            ob[131072 + (size_t)tg * TOPK + r] = ev[r] * inv;     // chunk 1: weight
        }
    }
#undef LOAD_SET
#undef WRITE_SET
}

extern "C" void kernel_launch(void* const* d_in, const int* in_sizes, int n_in,
                              void* d_out, int out_size, void* d_ws, size_t ws_size,
                              hipStream_t stream) {
    const float* hs = (const float*)d_in[0];   // [16384, 7168] f32
    const float* wt = (const float*)d_in[1];   // [256, 7168] f32
    float* ob = (float*)d_out;                 // f32[393216]: idx | weight | row

    if (ws_size >= (size_t)NEXP * HID * 2) {
        unsigned short* wb = (unsigned short*)d_ws;
        wconv<<<dim3(NEXP * HID / 4 / 256), dim3(256), 0, stream>>>(wt, wb);
        moe_gate_mfma<true><<<dim3(NTOK / BT), dim3(512), 0, stream>>>(hs, wt, wb, ob);
    } else {
        moe_gate_mfma<false><<<dim3(NTOK / BT), dim3(512), 0, stream>>>(hs, wt, nullptr, ob);
    }
    moe_rows<<<dim3(512), dim3(256), 0, stream>>>(ob);
}